// Round 12
// baseline (297.048 us; speedup 1.0000x reference)
//
#include <hip/hip_runtime.h>
#include <math.h>

#define N_NODES 50000
#define N_EDGES 800000
#define DUMMY   50000   // index of the zeroed dummy row in xh / h1h

typedef __attribute__((ext_vector_type(4))) _Float16 half4;
typedef __attribute__((ext_vector_type(8))) _Float16 half8;
typedef __attribute__((ext_vector_type(4))) float f32x4;

// Weight fragment buffer layout (half8 units): 92 frags x 2 (hi/lo) x 64 lanes.
#define F_W1A 0
#define F_W1B (16 * 128)
#define F_W2A (48 * 128)
#define F_W2B (80 * 128)

#define SCATTER_BLOCKS 3128
#define PREP_BLOCKS    3149

// ---------------------------------------------------------------------------
// Merged prep + scatter. Blocks [0, SCATTER_BLOCKS) do the XCD-sliced ELL
// scatter (latency/atomic-bound); the rest do streaming prep (x->fp16,
// dummy rows, weight fragmentation). The two roles co-reside on the CUs so
// prep's bandwidth hides under scatter's atomic latency. Cursors are zeroed
// by a preceding hipMemsetAsync.
// ---------------------------------------------------------------------------
__global__ __launch_bounds__(256) void prep_scatter(
    const int* __restrict__ src, const int* __restrict__ dst,
    int* __restrict__ cursor8, int* __restrict__ ovcur,
    unsigned short* __restrict__ ellp, unsigned short* __restrict__ ovell,
    const float4* __restrict__ in, half4* __restrict__ xh4, half4* __restrict__ h1dummy,
    const float* __restrict__ w1a, const float* __restrict__ w1b,
    const float* __restrict__ w2a, const float* __restrict__ w2b,
    half8* __restrict__ wfrag)
{
    if (blockIdx.x < SCATTER_BLOCKS) {
        int g = blockIdx.x & 7;
        int el = (blockIdx.x >> 3) * 256 + threadIdx.x;
        if (el >= 100000) return;
        int e = g * 100000 + el;
        int d = dst[e];
        unsigned short s = (unsigned short)src[e];
        int slot = atomicAdd(&cursor8[g * 50000 + d], 1);
        if (slot < 8) ellp[(size_t)(g * 50000 + d) * 8 + slot] = s;
        else {
            int o = atomicAdd(&ovcur[d], 1);
            if (o < 16) ovell[d * 16 + o] = s;
        }
        return;
    }
    int i = (blockIdx.x - SCATTER_BLOCKS) * 256 + threadIdx.x;
    if (i < 800000) {
        float4 v = in[i];
        half4 h;
        h[0] = (_Float16)v.x; h[1] = (_Float16)v.y;
        h[2] = (_Float16)v.z; h[3] = (_Float16)v.w;
        xh4[i] = h;
    } else if (i < 800016) {           // xh dummy row (64 fp16)
        half4 zer = {(_Float16)0.f, (_Float16)0.f, (_Float16)0.f, (_Float16)0.f};
        xh4[i] = zer;
    }
    if (i < 32) {                      // h1h dummy row (128 fp16)
        half4 zer = {(_Float16)0.f, (_Float16)0.f, (_Float16)0.f, (_Float16)0.f};
        h1dummy[i] = zer;
    }
    int j = i - 800032;
    if (j >= 0 && j < 5888) {
        int l = j & 63, f = j >> 6;
        const float* W; int fi, s, ct, Nw, base;
        if (f < 16)      { W = w1a; fi = f;      s = fi >> 3; ct = fi & 7;    Nw = 128; base = F_W1A; }
        else if (f < 48) { W = w1b; fi = f - 16; s = fi >> 3; ct = fi & 7;    Nw = 128; base = F_W1B; }
        else if (f < 80) { W = w2a; fi = f - 48; s = fi >> 3; ct = fi & 7;    Nw = 128; base = F_W2A; }
        else             { W = w2b; fi = f - 80; s = fi / 3;  ct = fi - s*3;  Nw = 40;  base = F_W2B; }
        int c = ct * 16 + (l & 15);
        int k0 = s * 32 + (l >> 4) * 8;
        half8 hi, lo;
        #pragma unroll
        for (int t = 0; t < 8; ++t) {
            float wv = (c < Nw) ? W[(k0 + t) * Nw + c] : 0.0f;
            _Float16 h = (_Float16)wv;
            hi[t] = h;
            lo[t] = (_Float16)(wv - (float)h);
        }
        wfrag[base + (fi * 2 + 0) * 64 + l] = hi;
        wfrag[base + (fi * 2 + 1) * 64 + l] = lo;
    }
}

// ---------------------------------------------------------------------------
// Column-blocked compact + gather d=64. blockIdx.y = column-group cg in
// {0,1}: this pass reads only cols [cg*32, cg*32+32) of xh (3.2 MB slice ->
// fits per-XCD L2, random re-reads become L2 hits). Each pass independently
// ballot-compacts from the read-only ELL planes (no cross-pass race); pass 0
// additionally writes the compacted ell + deg for gather128.
// Lane = (q=half8 chunk 0..3, p=parity 0..15): whole <=64-neighbor list in
// ONE iteration of 4 independent 16-B loads.
// ---------------------------------------------------------------------------
__global__ __launch_bounds__(256) void gather64c(const half8* __restrict__ rows,
    const int* __restrict__ cursor8, const int* __restrict__ ovcur,
    const unsigned short* __restrict__ ellp, const unsigned short* __restrict__ ovell,
    unsigned short* __restrict__ ell, int* __restrict__ deg,
    const float* __restrict__ epsp, half8* __restrict__ z)
{
    __shared__ unsigned short buf[4][80];
    const float eps = 1.0f + epsp[0];
    const int cg = blockIdx.y;
    const int lane = threadIdx.x & 63;
    const int w = threadIdx.x >> 6;
    const int q = lane & 3, p = lane >> 2;
    const int gpl = lane >> 3, sl = lane & 7;   // compact: plane, slot
    const int wid = blockIdx.x * 4 + w;
    const int wstep = gridDim.x * 4;

    for (int node = wid; node < N_NODES; node += wstep) {
        // --- compact (from read-only planes; duplicated per pass) ---
        int cgn = min(cursor8[gpl * 50000 + node], 8);
        bool valid = sl < cgn;
        unsigned short v = ellp[(size_t)(gpl * 50000 + node) * 8 + sl];
        unsigned long long mask = __ballot(valid);
        int total = __popcll(mask);
        int pos = __popcll(mask & ((1ULL << lane) - 1ULL));
        if (valid) buf[w][pos] = v;
        int ov = min(ovcur[node], 16);
        if (lane < ov) buf[w][total + lane] = ovell[node * 16 + lane];
        int tot = min(total + ov, 64);
        unsigned short e = (lane < tot) ? buf[w][lane] : (unsigned short)DUMMY;
        if (cg == 0) {
            ell[((size_t)node << 6) + lane] = e;
            if (lane == 0) deg[node] = tot;
        }
        int eidx = e;
        // --- gather: one iteration, 4 loads of this pass's 32-col slice ---
        int s0 = __shfl(eidx, p);
        int s1 = __shfl(eidx, 16 + p);
        int s2 = __shfl(eidx, 32 + p);
        int s3 = __shfl(eidx, 48 + p);
        int base = cg * 4 + q;
        half8 v0 = rows[s0 * 8 + base];
        half8 v1 = rows[s1 * 8 + base];
        half8 v2 = rows[s2 * 8 + base];
        half8 v3 = rows[s3 * 8 + base];
        float acc[8];
        #pragma unroll
        for (int j = 0; j < 8; ++j)
            acc[j] = ((float)v0[j] + (float)v1[j]) + ((float)v2[j] + (float)v3[j]);
        #pragma unroll
        for (int j = 0; j < 8; ++j) {
            acc[j] += __shfl_xor(acc[j], 4);
            acc[j] += __shfl_xor(acc[j], 8);
            acc[j] += __shfl_xor(acc[j], 16);
            acc[j] += __shfl_xor(acc[j], 32);
        }
        if (p == 0) {
            half8 sv = rows[node * 8 + base];
            half8 o;
            #pragma unroll
            for (int j = 0; j < 8; ++j) o[j] = (_Float16)fmaf(eps, (float)sv[j], acc[j]);
            z[node * 8 + base] = o;
        }
    }
}

// ---------------------------------------------------------------------------
// Column-blocked gather d=128. blockIdx.y = cg in {0..3}: pass slice 3.2 MB
// -> per-XCD-L2-resident. Consumes the DUMMY-padded ell; deg not needed.
// ---------------------------------------------------------------------------
__global__ __launch_bounds__(256) void gather128(const half8* __restrict__ rows,
    const unsigned short* __restrict__ ell,
    const float* __restrict__ epsp, half8* __restrict__ z)
{
    const float eps = 1.0f + epsp[0];
    const int cg = blockIdx.y;
    const int lane = threadIdx.x & 63;
    const int q = lane & 3, p = lane >> 2;
    const int wid = blockIdx.x * 4 + (threadIdx.x >> 6);
    const int wstep = gridDim.x * 4;

    for (int node = wid; node < N_NODES; node += wstep) {
        int eidx = ell[((size_t)node << 6) + lane];   // DUMMY-padded
        int s0 = __shfl(eidx, p);
        int s1 = __shfl(eidx, 16 + p);
        int s2 = __shfl(eidx, 32 + p);
        int s3 = __shfl(eidx, 48 + p);
        int base = cg * 4 + q;
        half8 v0 = rows[s0 * 16 + base];
        half8 v1 = rows[s1 * 16 + base];
        half8 v2 = rows[s2 * 16 + base];
        half8 v3 = rows[s3 * 16 + base];
        float acc[8];
        #pragma unroll
        for (int j = 0; j < 8; ++j)
            acc[j] = ((float)v0[j] + (float)v1[j]) + ((float)v2[j] + (float)v3[j]);
        #pragma unroll
        for (int j = 0; j < 8; ++j) {
            acc[j] += __shfl_xor(acc[j], 4);
            acc[j] += __shfl_xor(acc[j], 8);
            acc[j] += __shfl_xor(acc[j], 16);
            acc[j] += __shfl_xor(acc[j], 32);
        }
        if (p == 0) {
            half8 sv = rows[node * 16 + base];
            half8 o;
            #pragma unroll
            for (int j = 0; j < 8; ++j) o[j] = (_Float16)fmaf(eps, (float)sv[j], acc[j]);
            z[node * 16 + base] = o;
        }
    }
}

// ---------------------------------------------------------------------------
// Fused 2-layer MLP (R11 v2): weights from pre-fragmented global buffer,
// wave-private 4KB LDS mid tile, no barriers.
// ---------------------------------------------------------------------------
template<int KA, int NB, int EPI>
__global__ __launch_bounds__(256) void fused_mlp(const _Float16* __restrict__ A,
    const half8* __restrict__ wAF, const float* __restrict__ bA,
    const half8* __restrict__ wBF, const float* __restrict__ bB,
    void* __restrict__ Cout)
{
    constexpr int SA = KA / 32, CTB = NB / 16;
    __shared__ char mid[4][4096];
    const int tid = threadIdx.x;
    const int lane = tid & 63;
    const int wave = tid >> 6;
    const int gg = lane >> 4, r16 = lane & 15;
    const int tile = blockIdx.x * 4 + wave;
    if (tile >= (N_NODES + 15) / 16) return;
    char* my = mid[wave];

    // ---- layer A: KA -> 128, relu ----
    const _Float16* Ar = A + (size_t)(tile * 16 + r16) * KA;
    f32x4 acc[8];
    #pragma unroll
    for (int ct = 0; ct < 8; ++ct) acc[ct] = (f32x4){0.f, 0.f, 0.f, 0.f};
    #pragma unroll
    for (int s = 0; s < SA; ++s) {
        half8 a = *(const half8*)(Ar + s * 32 + gg * 8);
        #pragma unroll
        for (int ct = 0; ct < 8; ++ct) {
            half8 bh = wAF[((s * 8 + ct) * 2 + 0) * 64 + lane];
            half8 bo = wAF[((s * 8 + ct) * 2 + 1) * 64 + lane];
            acc[ct] = __builtin_amdgcn_mfma_f32_16x16x32_f16(a, bh, acc[ct], 0, 0, 0);
            acc[ct] = __builtin_amdgcn_mfma_f32_16x16x32_f16(a, bo, acc[ct], 0, 0, 0);
        }
    }
    #pragma unroll
    for (int ct = 0; ct < 8; ++ct) {
        float bb = bA[ct * 16 + r16];
        #pragma unroll
        for (int r = 0; r < 4; ++r) {
            int row = gg * 4 + r;
            float v = fmaxf(acc[ct][r] + bb, 0.0f);
            int off = (row << 8) + ((ct * 16 + r16) << 1);
            off ^= (row & 7) << 4;
            *(_Float16*)(my + off) = (_Float16)v;
        }
    }

    // ---- layer B: 128 -> NB ----
    half8 a2[4];
    #pragma unroll
    for (int s = 0; s < 4; ++s) {
        int off = (r16 << 8) + (s << 6) + (gg << 4);
        off ^= (r16 & 7) << 4;
        a2[s] = *(const half8*)(my + off);
    }
    f32x4 acc2[CTB];
    #pragma unroll
    for (int ct = 0; ct < CTB; ++ct) acc2[ct] = (f32x4){0.f, 0.f, 0.f, 0.f};
    #pragma unroll
    for (int s = 0; s < 4; ++s) {
        #pragma unroll
        for (int ct = 0; ct < CTB; ++ct) {
            half8 bh = wBF[((s * CTB + ct) * 2 + 0) * 64 + lane];
            half8 bo = wBF[((s * CTB + ct) * 2 + 1) * 64 + lane];
            acc2[ct] = __builtin_amdgcn_mfma_f32_16x16x32_f16(a2[s], bh, acc2[ct], 0, 0, 0);
            acc2[ct] = __builtin_amdgcn_mfma_f32_16x16x32_f16(a2[s], bo, acc2[ct], 0, 0, 0);
        }
    }

    if (EPI == 0) {
        _Float16* C = (_Float16*)Cout;
        #pragma unroll
        for (int ct = 0; ct < CTB; ++ct) {
            float bb = bB[ct * 16 + r16];
            #pragma unroll
            for (int r = 0; r < 4; ++r) {
                int row = tile * 16 + gg * 4 + r;
                float v = fmaxf(acc2[ct][r] + bb, 0.0f);
                C[(size_t)row * NB + ct * 16 + r16] = (_Float16)v;
            }
        }
    } else {
        float* C = (float*)Cout;
        const bool va2 = r16 < 8;
        float bl0 = bB[r16], bl1 = bB[16 + r16];
        float bl2 = va2 ? bB[32 + r16] : 0.0f;
        #pragma unroll
        for (int r = 0; r < 4; ++r) {
            int row = tile * 16 + gg * 4 + r;
            float v0 = acc2[0][r] + bl0;
            float v1 = acc2[1][r] + bl1;
            float v2 = acc2[2][r] + bl2;
            float mx = fmaxf(fmaxf(v0, v1), va2 ? v2 : -__builtin_inff());
            mx = fmaxf(mx, __shfl_xor(mx, 1));
            mx = fmaxf(mx, __shfl_xor(mx, 2));
            mx = fmaxf(mx, __shfl_xor(mx, 4));
            mx = fmaxf(mx, __shfl_xor(mx, 8));
            float sm = expf(v0 - mx) + expf(v1 - mx) + (va2 ? expf(v2 - mx) : 0.f);
            sm += __shfl_xor(sm, 1);
            sm += __shfl_xor(sm, 2);
            sm += __shfl_xor(sm, 4);
            sm += __shfl_xor(sm, 8);
            float ls = logf(sm) + mx;
            C[row * 40 + r16] = v0 - ls;
            C[row * 40 + 16 + r16] = v1 - ls;
            if (va2) C[row * 40 + 32 + r16] = v2 - ls;
        }
    }
}

// ---------------------------------------------------------------------------
extern "C" void kernel_launch(void* const* d_in, const int* in_sizes, int n_in,
                              void* d_out, int out_size, void* d_ws, size_t ws_size,
                              hipStream_t stream) {
    const float* x    = (const float*)d_in[0];
    const int*   ei   = (const int*)d_in[1];
    const float* w1a  = (const float*)d_in[2];
    const float* b1a  = (const float*)d_in[3];
    const float* w1b  = (const float*)d_in[4];
    const float* b1b  = (const float*)d_in[5];
    const float* eps1 = (const float*)d_in[6];
    const float* w2a  = (const float*)d_in[7];
    const float* b2a  = (const float*)d_in[8];
    const float* w2b  = (const float*)d_in[9];
    const float* b2b  = (const float*)d_in[10];
    const float* eps2 = (const float*)d_in[11];
    float* out = (float*)d_out;

    const int* srcIdx = ei;
    const int* dstIdx = ei + N_EDGES;

    // Workspace layout (~55 MB):
    //   cursor8 1.6M  @0          (zeroed together with ovcur by memset)
    //   ovcur   200K  @1600000
    //   ellp    6.4M  @1800000
    //   ovell   1.6M  @8200000
    //   ell     6.4M  @9800000
    //   deg     200K  @16200000
    //   wfrag   188K  @16400000
    //   xh      6.400128M @16600000   (50001 x 64 fp16; row 50000 = 0)
    //   z1h     6.4M  @23000192
    //   h1h    12.800256M @29400192   (50001 x 128 fp16; row 50000 = 0)
    //   z2h    12.8M  @42200448
    char* ws = (char*)d_ws;
    int*            cursor8 = (int*)(ws);
    int*            ovcur   = (int*)(ws + 1600000);
    unsigned short* ellp    = (unsigned short*)(ws + 1800000);
    unsigned short* ovell   = (unsigned short*)(ws + 8200000);
    unsigned short* ell     = (unsigned short*)(ws + 9800000);
    int*            deg     = (int*)(ws + 16200000);
    half8*          wfrag   = (half8*)(ws + 16400000);
    _Float16*       xh      = (_Float16*)(ws + 16600000);
    _Float16*       z1h     = (_Float16*)(ws + 23000192);
    _Float16*       h1h     = (_Float16*)(ws + 29400192);
    _Float16*       z2h     = (_Float16*)(ws + 42200448);
    half4*          h1dummy = (half4*)(h1h + (size_t)DUMMY * 128);

    hipMemsetAsync(cursor8, 0, 1800000, stream);   // cursor8 + ovcur

    prep_scatter<<<SCATTER_BLOCKS + PREP_BLOCKS, 256, 0, stream>>>(
        srcIdx, dstIdx, cursor8, ovcur, ellp, ovell,
        (const float4*)x, (half4*)xh, h1dummy, w1a, w1b, w2a, w2b, wfrag);

    gather64c<<<dim3(1024, 2), 256, 0, stream>>>((const half8*)xh, cursor8, ovcur,
                                                 ellp, ovell, ell, deg, eps1, (half8*)z1h);
    fused_mlp<64, 128, 0><<<782, 256, 0, stream>>>(z1h, wfrag + F_W1A, b1a,
                                                   wfrag + F_W1B, b1b, h1h);
    gather128<<<dim3(1024, 4), 256, 0, stream>>>((const half8*)h1h, ell, eps2, (half8*)z2h);
    fused_mlp<128, 48, 1><<<782, 256, 0, stream>>>(z2h, wfrag + F_W2A, b2a,
                                                   wfrag + F_W2B, b2b, out);
}

// Round 13
// 202.103 us; speedup vs baseline: 1.4698x; 1.4698x over previous
//
#include <hip/hip_runtime.h>
#include <math.h>

#define N_NODES 50000
#define N_EDGES 800000
#define DUMMY   50000   // index of the zeroed dummy row in xh / h1h

typedef __attribute__((ext_vector_type(4))) _Float16 half4;
typedef __attribute__((ext_vector_type(8))) _Float16 half8;
typedef __attribute__((ext_vector_type(4))) float f32x4;

// Weight fragment buffer (half8 units, single fp16 precision): 92 frags x 64.
#define F_W1A 0
#define F_W1B (16 * 64)
#define F_W2A (48 * 64)
#define F_W2B (80 * 64)

#define SCATTER_BLOCKS 3128
#define PREP_BLOCKS    3149

// ---------------------------------------------------------------------------
// Merged prep + scatter. Blocks [0, SCATTER_BLOCKS): XCD-sliced ELL scatter
// (latency/atomic-bound). Remaining blocks: streaming prep (x->fp16, dummy
// rows, fp16 weight fragments). Roles co-reside so prep bandwidth hides under
// scatter atomics. Cursors zeroed by preceding hipMemsetAsync.
// ---------------------------------------------------------------------------
__global__ __launch_bounds__(256) void prep_scatter(
    const int* __restrict__ src, const int* __restrict__ dst,
    int* __restrict__ cursor8, int* __restrict__ ovcur,
    unsigned short* __restrict__ ellp, unsigned short* __restrict__ ovell,
    const float4* __restrict__ in, half4* __restrict__ xh4, half4* __restrict__ h1dummy,
    const float* __restrict__ w1a, const float* __restrict__ w1b,
    const float* __restrict__ w2a, const float* __restrict__ w2b,
    half8* __restrict__ wfrag)
{
    if (blockIdx.x < SCATTER_BLOCKS) {
        int g = blockIdx.x & 7;
        int el = (blockIdx.x >> 3) * 256 + threadIdx.x;
        if (el >= 100000) return;
        int e = g * 100000 + el;
        int d = dst[e];
        unsigned short s = (unsigned short)src[e];
        int slot = atomicAdd(&cursor8[g * 50000 + d], 1);
        if (slot < 8) ellp[(size_t)(g * 50000 + d) * 8 + slot] = s;
        else {
            int o = atomicAdd(&ovcur[d], 1);
            if (o < 16) ovell[d * 16 + o] = s;
        }
        return;
    }
    int i = (blockIdx.x - SCATTER_BLOCKS) * 256 + threadIdx.x;
    if (i < 800000) {
        float4 v = in[i];
        half4 h;
        h[0] = (_Float16)v.x; h[1] = (_Float16)v.y;
        h[2] = (_Float16)v.z; h[3] = (_Float16)v.w;
        xh4[i] = h;
    } else if (i < 800016) {           // xh dummy row (64 fp16)
        half4 zer = {(_Float16)0.f, (_Float16)0.f, (_Float16)0.f, (_Float16)0.f};
        xh4[i] = zer;
    }
    if (i < 32) {                      // h1h dummy row (128 fp16)
        half4 zer = {(_Float16)0.f, (_Float16)0.f, (_Float16)0.f, (_Float16)0.f};
        h1dummy[i] = zer;
    }
    int j = i - 800032;
    if (j >= 0 && j < 5888) {
        int l = j & 63, f = j >> 6;
        const float* W; int fi, s, ct, Nw, base;
        if (f < 16)      { W = w1a; fi = f;      s = fi >> 3; ct = fi & 7;    Nw = 128; base = F_W1A; }
        else if (f < 48) { W = w1b; fi = f - 16; s = fi >> 3; ct = fi & 7;    Nw = 128; base = F_W1B; }
        else if (f < 80) { W = w2a; fi = f - 48; s = fi >> 3; ct = fi & 7;    Nw = 128; base = F_W2A; }
        else             { W = w2b; fi = f - 80; s = fi / 3;  ct = fi - s*3;  Nw = 40;  base = F_W2B; }
        int c = ct * 16 + (l & 15);
        int k0 = s * 32 + (l >> 4) * 8;
        half8 hi;
        #pragma unroll
        for (int t = 0; t < 8; ++t) {
            float wv = (c < Nw) ? W[(k0 + t) * Nw + c] : 0.0f;
            hi[t] = (_Float16)wv;
        }
        wfrag[base + fi * 64 + l] = hi;
    }
}

// ---------------------------------------------------------------------------
// In-wave ballot-compact of the 8 ELL planes + overflow -> DUMMY-padded
// 64-entry neighbor list in registers. Shared by both gathers.
// ---------------------------------------------------------------------------
__device__ __forceinline__ int compact_nbrs(int node, int lane, int w,
    const int* __restrict__ cursor8, const int* __restrict__ ovcur,
    const unsigned short* __restrict__ ellp, const unsigned short* __restrict__ ovell,
    unsigned short (*buf)[80], int* tot_out)
{
    const int gpl = lane >> 3, sl = lane & 7;
    int cg = min(cursor8[gpl * 50000 + node], 8);
    bool valid = sl < cg;
    unsigned short v = ellp[(size_t)(gpl * 50000 + node) * 8 + sl];
    unsigned long long mask = __ballot(valid);
    int total = __popcll(mask);
    int pos = __popcll(mask & ((1ULL << lane) - 1ULL));
    if (valid) buf[w][pos] = v;
    int ov = min(ovcur[node], 16);
    if (lane < ov) buf[w][total + lane] = ovell[node * 16 + lane];
    int tot = min(total + ov, 64);
    *tot_out = tot;
    return (lane < tot) ? (int)buf[w][lane] : DUMMY;
}

// ---------------------------------------------------------------------------
// Gather d=64: compact + gather. lane=(q=half8 chunk 0..7, p=parity 0..7),
// 32 neighbors/iter, 4 independent 16-B loads per lane.
// ---------------------------------------------------------------------------
__global__ __launch_bounds__(256) void gather64c(const half8* __restrict__ rows,
    const int* __restrict__ cursor8, const int* __restrict__ ovcur,
    const unsigned short* __restrict__ ellp, const unsigned short* __restrict__ ovell,
    const float* __restrict__ epsp, half8* __restrict__ z)
{
    __shared__ unsigned short buf[4][80];
    const float eps = 1.0f + epsp[0];
    const int lane = threadIdx.x & 63;
    const int w = threadIdx.x >> 6;
    const int q = lane & 7, p = lane >> 3;
    const int wid = blockIdx.x * 4 + w;
    const int wstep = gridDim.x * 4;

    for (int node = wid; node < N_NODES; node += wstep) {
        int tot;
        int eidx = compact_nbrs(node, lane, w, cursor8, ovcur, ellp, ovell, buf, &tot);
        float acc[8];
        #pragma unroll
        for (int j = 0; j < 8; ++j) acc[j] = 0.f;
        for (int i = 0; i < tot; i += 32) {
            int s0 = __shfl(eidx, i + p);
            int s1 = __shfl(eidx, i + 8 + p);
            int s2 = __shfl(eidx, i + 16 + p);
            int s3 = __shfl(eidx, i + 24 + p);
            half8 v0 = rows[s0 * 8 + q];
            half8 v1 = rows[s1 * 8 + q];
            half8 v2 = rows[s2 * 8 + q];
            half8 v3 = rows[s3 * 8 + q];
            #pragma unroll
            for (int j = 0; j < 8; ++j)
                acc[j] += ((float)v0[j] + (float)v1[j]) + ((float)v2[j] + (float)v3[j]);
        }
        #pragma unroll
        for (int j = 0; j < 8; ++j) {
            acc[j] += __shfl_xor(acc[j], 8);
            acc[j] += __shfl_xor(acc[j], 16);
            acc[j] += __shfl_xor(acc[j], 32);
        }
        if (p == 0) {
            half8 sv = rows[node * 8 + q];
            half8 o;
            #pragma unroll
            for (int j = 0; j < 8; ++j) o[j] = (_Float16)fmaf(eps, (float)sv[j], acc[j]);
            z[node * 8 + q] = o;
        }
    }
}

// ---------------------------------------------------------------------------
// Gather d=128: compact + gather. lane=(q=chunk 0..15, p=parity 0..3),
// 16 neighbors/iter.
// ---------------------------------------------------------------------------
__global__ __launch_bounds__(256) void gather128c(const half8* __restrict__ rows,
    const int* __restrict__ cursor8, const int* __restrict__ ovcur,
    const unsigned short* __restrict__ ellp, const unsigned short* __restrict__ ovell,
    const float* __restrict__ epsp, half8* __restrict__ z)
{
    __shared__ unsigned short buf[4][80];
    const float eps = 1.0f + epsp[0];
    const int lane = threadIdx.x & 63;
    const int w = threadIdx.x >> 6;
    const int q = lane & 15, p = lane >> 4;
    const int wid = blockIdx.x * 4 + w;
    const int wstep = gridDim.x * 4;

    for (int node = wid; node < N_NODES; node += wstep) {
        int tot;
        int eidx = compact_nbrs(node, lane, w, cursor8, ovcur, ellp, ovell, buf, &tot);
        float acc[8];
        #pragma unroll
        for (int j = 0; j < 8; ++j) acc[j] = 0.f;
        for (int i = 0; i < tot; i += 16) {
            int s0 = __shfl(eidx, i + p);
            int s1 = __shfl(eidx, i + 4 + p);
            int s2 = __shfl(eidx, i + 8 + p);
            int s3 = __shfl(eidx, i + 12 + p);
            half8 v0 = rows[s0 * 16 + q];
            half8 v1 = rows[s1 * 16 + q];
            half8 v2 = rows[s2 * 16 + q];
            half8 v3 = rows[s3 * 16 + q];
            #pragma unroll
            for (int j = 0; j < 8; ++j)
                acc[j] += ((float)v0[j] + (float)v1[j]) + ((float)v2[j] + (float)v3[j]);
        }
        #pragma unroll
        for (int j = 0; j < 8; ++j) {
            acc[j] += __shfl_xor(acc[j], 16);
            acc[j] += __shfl_xor(acc[j], 32);
        }
        if (p == 0) {
            half8 sv = rows[node * 16 + q];
            half8 o;
            #pragma unroll
            for (int j = 0; j < 8; ++j) o[j] = (_Float16)fmaf(eps, (float)sv[j], acc[j]);
            z[node * 16 + q] = o;
        }
    }
}

// ---------------------------------------------------------------------------
// Fused 2-layer MLP: single-fp16 weights from pre-fragmented global buffer
// (halved MFMA count vs hi/lo), wave-private 4KB LDS mid tile, no barriers.
// ---------------------------------------------------------------------------
template<int KA, int NB, int EPI>
__global__ __launch_bounds__(256) void fused_mlp(const _Float16* __restrict__ A,
    const half8* __restrict__ wAF, const float* __restrict__ bA,
    const half8* __restrict__ wBF, const float* __restrict__ bB,
    void* __restrict__ Cout)
{
    constexpr int SA = KA / 32, CTB = NB / 16;
    __shared__ char mid[4][4096];
    const int tid = threadIdx.x;
    const int lane = tid & 63;
    const int wave = tid >> 6;
    const int gg = lane >> 4, r16 = lane & 15;
    const int tile = blockIdx.x * 4 + wave;
    if (tile >= (N_NODES + 15) / 16) return;
    char* my = mid[wave];

    // ---- layer A: KA -> 128, relu ----
    const _Float16* Ar = A + (size_t)(tile * 16 + r16) * KA;
    f32x4 acc[8];
    #pragma unroll
    for (int ct = 0; ct < 8; ++ct) acc[ct] = (f32x4){0.f, 0.f, 0.f, 0.f};
    #pragma unroll
    for (int s = 0; s < SA; ++s) {
        half8 a = *(const half8*)(Ar + s * 32 + gg * 8);
        #pragma unroll
        for (int ct = 0; ct < 8; ++ct) {
            half8 bh = wAF[(s * 8 + ct) * 64 + lane];
            acc[ct] = __builtin_amdgcn_mfma_f32_16x16x32_f16(a, bh, acc[ct], 0, 0, 0);
        }
    }
    #pragma unroll
    for (int ct = 0; ct < 8; ++ct) {
        float bb = bA[ct * 16 + r16];
        #pragma unroll
        for (int r = 0; r < 4; ++r) {
            int row = gg * 4 + r;
            float v = fmaxf(acc[ct][r] + bb, 0.0f);
            int off = (row << 8) + ((ct * 16 + r16) << 1);
            off ^= (row & 7) << 4;
            *(_Float16*)(my + off) = (_Float16)v;
        }
    }

    // ---- layer B: 128 -> NB ----
    half8 a2[4];
    #pragma unroll
    for (int s = 0; s < 4; ++s) {
        int off = (r16 << 8) + (s << 6) + (gg << 4);
        off ^= (r16 & 7) << 4;
        a2[s] = *(const half8*)(my + off);
    }
    f32x4 acc2[CTB];
    #pragma unroll
    for (int ct = 0; ct < CTB; ++ct) acc2[ct] = (f32x4){0.f, 0.f, 0.f, 0.f};
    #pragma unroll
    for (int s = 0; s < 4; ++s) {
        #pragma unroll
        for (int ct = 0; ct < CTB; ++ct) {
            half8 bh = wBF[(s * CTB + ct) * 64 + lane];
            acc2[ct] = __builtin_amdgcn_mfma_f32_16x16x32_f16(a2[s], bh, acc2[ct], 0, 0, 0);
        }
    }

    if (EPI == 0) {
        _Float16* C = (_Float16*)Cout;
        #pragma unroll
        for (int ct = 0; ct < CTB; ++ct) {
            float bb = bB[ct * 16 + r16];
            #pragma unroll
            for (int r = 0; r < 4; ++r) {
                int row = tile * 16 + gg * 4 + r;
                float v = fmaxf(acc2[ct][r] + bb, 0.0f);
                C[(size_t)row * NB + ct * 16 + r16] = (_Float16)v;
            }
        }
    } else {
        float* C = (float*)Cout;
        const bool va2 = r16 < 8;
        float bl0 = bB[r16], bl1 = bB[16 + r16];
        float bl2 = va2 ? bB[32 + r16] : 0.0f;
        #pragma unroll
        for (int r = 0; r < 4; ++r) {
            int row = tile * 16 + gg * 4 + r;
            float v0 = acc2[0][r] + bl0;
            float v1 = acc2[1][r] + bl1;
            float v2 = acc2[2][r] + bl2;
            float mx = fmaxf(fmaxf(v0, v1), va2 ? v2 : -__builtin_inff());
            mx = fmaxf(mx, __shfl_xor(mx, 1));
            mx = fmaxf(mx, __shfl_xor(mx, 2));
            mx = fmaxf(mx, __shfl_xor(mx, 4));
            mx = fmaxf(mx, __shfl_xor(mx, 8));
            float sm = expf(v0 - mx) + expf(v1 - mx) + (va2 ? expf(v2 - mx) : 0.f);
            sm += __shfl_xor(sm, 1);
            sm += __shfl_xor(sm, 2);
            sm += __shfl_xor(sm, 4);
            sm += __shfl_xor(sm, 8);
            float ls = logf(sm) + mx;
            C[row * 40 + r16] = v0 - ls;
            C[row * 40 + 16 + r16] = v1 - ls;
            if (va2) C[row * 40 + 32 + r16] = v2 - ls;
        }
    }
}

// ---------------------------------------------------------------------------
extern "C" void kernel_launch(void* const* d_in, const int* in_sizes, int n_in,
                              void* d_out, int out_size, void* d_ws, size_t ws_size,
                              hipStream_t stream) {
    const float* x    = (const float*)d_in[0];
    const int*   ei   = (const int*)d_in[1];
    const float* w1a  = (const float*)d_in[2];
    const float* b1a  = (const float*)d_in[3];
    const float* w1b  = (const float*)d_in[4];
    const float* b1b  = (const float*)d_in[5];
    const float* eps1 = (const float*)d_in[6];
    const float* w2a  = (const float*)d_in[7];
    const float* b2a  = (const float*)d_in[8];
    const float* w2b  = (const float*)d_in[9];
    const float* b2b  = (const float*)d_in[10];
    const float* eps2 = (const float*)d_in[11];
    float* out = (float*)d_out;

    const int* srcIdx = ei;
    const int* dstIdx = ei + N_EDGES;

    // Workspace layout (~48.3 MB):
    //   cursor8 1.6M  @0          (zeroed with ovcur by memset)
    //   ovcur   200K  @1600000
    //   ellp    6.4M  @1800000
    //   ovell   1.6M  @8200000
    //   wfrag   94.2K @9800000    (92 frags x 64 half8, fp16 only)
    //   xh      6.400128M @9900000    (50001 x 64 fp16; row 50000 = 0)
    //   z1h     6.4M  @16300160
    //   h1h    12.800256M @22700160  (50001 x 128 fp16; row 50000 = 0)
    //   z2h    12.8M  @35500416
    char* ws = (char*)d_ws;
    int*            cursor8 = (int*)(ws);
    int*            ovcur   = (int*)(ws + 1600000);
    unsigned short* ellp    = (unsigned short*)(ws + 1800000);
    unsigned short* ovell   = (unsigned short*)(ws + 8200000);
    half8*          wfrag   = (half8*)(ws + 9800000);
    _Float16*       xh      = (_Float16*)(ws + 9900000);
    _Float16*       z1h     = (_Float16*)(ws + 16300160);
    _Float16*       h1h     = (_Float16*)(ws + 22700160);
    _Float16*       z2h     = (_Float16*)(ws + 35500416);
    half4*          h1dummy = (half4*)(h1h + (size_t)DUMMY * 128);

    hipMemsetAsync(cursor8, 0, 1800000, stream);   // cursor8 + ovcur

    prep_scatter<<<SCATTER_BLOCKS + PREP_BLOCKS, 256, 0, stream>>>(
        srcIdx, dstIdx, cursor8, ovcur, ellp, ovell,
        (const float4*)x, (half4*)xh, h1dummy, w1a, w1b, w2a, w2b, wfrag);

    gather64c<<<2048, 256, 0, stream>>>((const half8*)xh, cursor8, ovcur,
                                        ellp, ovell, eps1, (half8*)z1h);
    fused_mlp<64, 128, 0><<<782, 256, 0, stream>>>(z1h, wfrag + F_W1A, b1a,
                                                   wfrag + F_W1B, b1b, h1h);
    gather128c<<<2048, 256, 0, stream>>>((const half8*)h1h, cursor8, ovcur,
                                         ellp, ovell, eps2, (half8*)z2h);
    fused_mlp<128, 48, 1><<<782, 256, 0, stream>>>(z2h, wfrag + F_W2A, b2a,
                                                   wfrag + F_W2B, b2b, out);
}